// Round 10
// baseline (289.405 us; speedup 1.0000x reference)
//
#include <hip/hip_runtime.h>

#define IN_C 128
#define HID  64
#define NCLS 40
#define CHP  1024     // edges per scatter_part chunk
#define CHH  4096     // edges per bhist chunk
#define NB   1024     // padded bucket-array size (B <= 1024)

typedef float f32x4 __attribute__((ext_vector_type(4)));
typedef short s16x8 __attribute__((ext_vector_type(8)));

// ---- bf16 helpers: RTN pack, shift-unpack ----
static __device__ inline unsigned short f2bf(float f) {
    unsigned u = __float_as_uint(f);
    return (unsigned short)((u + 0x7FFF + ((u >> 16) & 1)) >> 16);
}

// truncation split: v = hi + lo with hi = top-16-bit truncation
static __device__ inline void split1(float v, unsigned short& hb, unsigned short& lb) {
    hb = (unsigned short)(__float_as_uint(v) >> 16);
    float vhi = __uint_as_float((unsigned)hb << 16);
    lb = (unsigned short)(__float_as_uint(v - vhi) >> 16);
}

static __device__ inline void split8(const f32x4 a0, const f32x4 a1, s16x8& hi, s16x8& lo) {
    float v[8] = {a0.x, a0.y, a0.z, a0.w, a1.x, a1.y, a1.z, a1.w};
#pragma unroll
    for (int j = 0; j < 8; ++j) {
        unsigned short hb, lb;
        split1(v[j], hb, lb);
        hi[j] = (short)hb;
        lo[j] = (short)lb;
    }
}

// ================= bucket histogram: bcnt[b] = #edges with dst>>7 == b ======

__global__ __launch_bounds__(256) void bhist_kernel(
    const int* __restrict__ dst, int* __restrict__ bcnt, int E, int B)
{
    __shared__ int h[NB];
    const int t = threadIdx.x;
    for (int i = t; i < NB; i += 256) h[i] = 0;
    __syncthreads();
    const int base = blockIdx.x * CHH;
    const int nE = min(CHH, E - base);
    for (int k = t; k < nE; k += 256) atomicAdd(&h[dst[base + k] >> 7], 1);
    __syncthreads();
    for (int b = t; b < B; b += 256) { int c = h[b]; if (c) atomicAdd(&bcnt[b], c); }
}

// ================= bucket scan: bptr = exclusive scan(bcnt), bfill = copy ====

__global__ __launch_bounds__(256) void bscan_kernel(
    const int* __restrict__ bcnt, int* __restrict__ bptr, int* __restrict__ bfill,
    int B, int E)
{
    __shared__ int s[256];
    const int t = threadIdx.x;
    int v[4]; int ts = 0;
#pragma unroll
    for (int j = 0; j < 4; ++j) {
        int idx = 4 * t + j;
        v[j] = (idx < B) ? bcnt[idx] : 0;
        ts += v[j];
    }
    s[t] = ts; __syncthreads();
    for (int off = 1; off < 256; off <<= 1) {
        int add = (t >= off) ? s[t - off] : 0;
        __syncthreads();
        s[t] += add;
        __syncthreads();
    }
    int run = s[t] - ts;
#pragma unroll
    for (int j = 0; j < 4; ++j) {
        int idx = 4 * t + j;
        if (idx < B) { bptr[idx] = run; bfill[idx] = run; run += v[j]; }
    }
    if (t == 0) bptr[B] = E;
}

// ====== coarse partition: part[] = edges grouped by dst>>7 =================
// packed word = (src << 7) | (dst & 127)

__global__ __launch_bounds__(256) void scatter_part(
    const int* __restrict__ src, const int* __restrict__ dst,
    int* __restrict__ bfill, int* __restrict__ part, int E, int B)
{
    __shared__ int cnt[NB], soff[NB], gpos[NB], sdata[256];
    __shared__ int stage[CHP], destg[CHP];
    const int t = threadIdx.x;
    const int base = blockIdx.x * CHP;
    const int nE = min(CHP, E - base);

    for (int i = t; i < NB; i += 256) cnt[i] = 0;
    __syncthreads();
    for (int k = t; k < nE; k += 256)
        atomicAdd(&cnt[dst[base + k] >> 7], 1);
    __syncthreads();
    int v[4]; int ts = 0;
#pragma unroll
    for (int j = 0; j < 4; ++j) { v[j] = cnt[4 * t + j]; ts += v[j]; }
    sdata[t] = ts; __syncthreads();
    for (int off = 1; off < 256; off <<= 1) {
        int add = (t >= off) ? sdata[t - off] : 0;
        __syncthreads();
        sdata[t] += add;
        __syncthreads();
    }
    int run = sdata[t] - ts;
#pragma unroll
    for (int j = 0; j < 4; ++j) { soff[4 * t + j] = run; run += v[j]; }
    __syncthreads();
    for (int b = t; b < B; b += 256) {
        int c = cnt[b];
        gpos[b] = c ? atomicAdd(&bfill[b], c) : 0;
    }
    __syncthreads();
    for (int i = t; i < NB; i += 256) cnt[i] = 0;
    __syncthreads();
    for (int k = t; k < nE; k += 256) {
        int d = dst[base + k];
        int b = d >> 7;
        int p = atomicAdd(&cnt[b], 1);
        int o = soff[b] + p;
        stage[o] = (src[base + k] << 7) | (d & 127);
        destg[o] = gpos[b] + p;
    }
    __syncthreads();
    for (int k = t; k < nE; k += 256)
        part[destg[k]] = stage[k];
}

// ====== fine sort within bucket -> CSR col, per-node ptr & dis ==============

__global__ __launch_bounds__(256) void fine_sort(
    const int* __restrict__ bptr, const int* __restrict__ part,
    int* __restrict__ col, int* __restrict__ ptr, float* __restrict__ dis,
    int n, int E)
{
    __shared__ int cnt[128], sc[128], cur[128];
    __shared__ int stage[3072];
    const int t = threadIdx.x;
    const int base = blockIdx.x << 7;
    const int nn = min(128, n - base);
    const int rstart = bptr[blockIdx.x];
    const int rend   = bptr[blockIdx.x + 1];

    if (t < 128) cnt[t] = 0;
    __syncthreads();
    for (int e = rstart + t; e < rend; e += 256)
        atomicAdd(&cnt[part[e] & 127], 1);
    __syncthreads();
    int v = (t < 128) ? cnt[t] : 0;
    if (t < 128) sc[t] = v;
    __syncthreads();
    for (int off = 1; off < 128; off <<= 1) {
        int add = (t < 128 && t >= off) ? sc[t - off] : 0;
        __syncthreads();
        if (t < 128) sc[t] += add;
        __syncthreads();
    }
    if (t < 128) cur[t] = sc[t] - v;
    if (t < nn) {
        ptr[base + t] = rstart + sc[t] - v;
        dis[base + t] = rsqrtf((float)(v + 1));
    }
    if (blockIdx.x == 0 && t == 0) ptr[n] = E;
    __syncthreads();
    for (int e = rstart + t; e < rend; e += 256) {
        int pk = part[e];
        int p = atomicAdd(&cur[pk & 127], 1);
        int s = pk >> 7;
        if (p < 3072) stage[p] = s;
        else col[rstart + p] = s;
    }
    __syncthreads();
    int sz = rend - rstart; if (sz > 3072) sz = 3072;
    for (int j = t; j < sz; j += 256) col[rstart + j] = stage[j];
}

// ====== GEMM1 (MFMA): hs1b = bf16((x @ W1) * dis[i]) ======================

__global__ __launch_bounds__(256) void gemm1_mfma(
    const float* __restrict__ x, const float* __restrict__ W1,
    const float* __restrict__ dis, unsigned short* __restrict__ hs1b, int n)
{
    const int wave = threadIdx.x >> 6;
    const int lane = threadIdx.x & 63;
    const int m    = lane & 15;
    const int q    = lane >> 4;
    const int col  = wave * 16 + m;

    s16x8 bhi[4], blo[4];
#pragma unroll
    for (int t = 0; t < 4; ++t) {
#pragma unroll
        for (int j = 0; j < 8; ++j) {
            int k = t * 32 + q * 8 + j;
            unsigned short hb, lb;
            split1(W1[k * HID + col], hb, lb);
            bhi[t][j] = (short)hb;
            blo[t][j] = (short)lb;
        }
    }

    const int nslab = n >> 4;
    for (int s = blockIdx.x; s < nslab; s += gridDim.x) {
        const float* xrow = x + (size_t)(s * 16 + m) * IN_C;
        f32x4 acc = {0.f, 0.f, 0.f, 0.f};
#pragma unroll
        for (int t = 0; t < 4; ++t) {
            f32x4 a0 = *(const f32x4*)(xrow + t * 32 + q * 8);
            f32x4 a1 = *(const f32x4*)(xrow + t * 32 + q * 8 + 4);
            s16x8 ahi, alo;
            split8(a0, a1, ahi, alo);
            acc = __builtin_amdgcn_mfma_f32_16x16x32_bf16(ahi, bhi[t], acc, 0, 0, 0);
            acc = __builtin_amdgcn_mfma_f32_16x16x32_bf16(alo, bhi[t], acc, 0, 0, 0);
            acc = __builtin_amdgcn_mfma_f32_16x16x32_bf16(ahi, blo[t], acc, 0, 0, 0);
        }
#pragma unroll
        for (int r = 0; r < 4; ++r) {
            int row = s * 16 + q * 4 + r;
            hs1b[(size_t)row * HID + col] = f2bf(acc[r] * dis[row]);
        }
    }
}

// ===== agg1: h1 = relu(dis*(sum + self) + b1), paired u32 gathers ==========
// row = 32 dwords. half 0 (lanes 0-31) even edges, half 1 odd edges.
// ZERO-ROW SENTINEL: lanes >= m carry myc = n (zeroed row); since ep <= 63
// always, shfl pulls the sentinel for out-of-range edges -> unconditional
// accumulate, no compares/selects in the hot loop. 32-bit row indexing.

__global__ __launch_bounds__(256) void agg1_kernel(
    const int* __restrict__ ptr, const int* __restrict__ col,
    const unsigned* __restrict__ hs1p, const float* __restrict__ dis,
    const float* __restrict__ b1, unsigned* __restrict__ h1p, int n)
{
    int wave = threadIdx.x >> 6, lane = threadIdx.x & 63;
    int i = blockIdx.x * 4 + wave;
    if (i >= n) return;
    const int h  = lane >> 5;
    const int hl = lane & 31;
    const int ZR = n;                       // zeroed sentinel row
    int start = ptr[i], end = ptr[i + 1];
    float acc0 = 0.f, acc1 = 0.f;
    for (int base = start; base < end; base += 64) {
        int m = end - base; if (m > 64) m = 64;
        int myc = (lane < m) ? col[base + lane] : ZR;
        int rounds = (m + 1) >> 1;          // 2 edges per round
        for (int j = 0; j < rounds; j += 8) {
            unsigned w[8];
#pragma unroll
            for (int u = 0; u < 8; ++u) {
                int s = __shfl(myc, 2 * (j + u) + h);   // <= 63 always
                w[u] = hs1p[(unsigned)s * 32u + (unsigned)hl];
            }
#pragma unroll
            for (int u = 0; u < 8; ++u) {
                acc0 += __uint_as_float(w[u] << 16);
                acc1 += __uint_as_float(w[u] & 0xffff0000u);
            }
        }
    }
    // fold halves (valid in lanes < 32)
    float o0 = acc0 + __shfl(acc0, (lane + 32) & 63);
    float o1 = acc1 + __shfl(acc1, (lane + 32) & 63);
    if (lane < 32) {
        unsigned sw = hs1p[(unsigned)i * 32u + (unsigned)lane];   // self-loop
        float d = dis[i];
        float v0 = (o0 + __uint_as_float(sw << 16)) * d + b1[2 * lane];
        float v1 = (o1 + __uint_as_float(sw & 0xffff0000u)) * d + b1[2 * lane + 1];
        v0 = v0 > 0.f ? v0 : 0.f;
        v1 = v1 > 0.f ? v1 : 0.f;
        h1p[(unsigned)i * 32u + (unsigned)lane] = (unsigned)f2bf(v0) | ((unsigned)f2bf(v1) << 16);
    }
}

// ====== GEMM2 (MFMA): hs2b = bf16((h1 @ W2) * dis[i]), h1 native bf16 ======

__global__ __launch_bounds__(192) void gemm2_mfma(
    const unsigned short* __restrict__ h1b, const float* __restrict__ W2,
    const float* __restrict__ dis, unsigned short* __restrict__ hs2b, int n)
{
    const int wave = threadIdx.x >> 6;
    const int lane = threadIdx.x & 63;
    const int m    = lane & 15;
    const int q    = lane >> 4;
    const int col  = wave * 16 + m;

    s16x8 bhi[2], blo[2];
#pragma unroll
    for (int t = 0; t < 2; ++t) {
#pragma unroll
        for (int j = 0; j < 8; ++j) {
            int k = t * 32 + q * 8 + j;
            float w = (col < NCLS) ? W2[k * NCLS + col] : 0.f;
            unsigned short hb, lb;
            split1(w, hb, lb);
            bhi[t][j] = (short)hb;
            blo[t][j] = (short)lb;
        }
    }

    const int nslab = n >> 4;
    for (int s = blockIdx.x; s < nslab; s += gridDim.x) {
        const unsigned short* hrow = h1b + (size_t)(s * 16 + m) * HID;
        f32x4 acc = {0.f, 0.f, 0.f, 0.f};
#pragma unroll
        for (int t = 0; t < 2; ++t) {
            s16x8 ahi = *(const s16x8*)(hrow + t * 32 + q * 8);   // native bf16 A
            acc = __builtin_amdgcn_mfma_f32_16x16x32_bf16(ahi, bhi[t], acc, 0, 0, 0);
            acc = __builtin_amdgcn_mfma_f32_16x16x32_bf16(ahi, blo[t], acc, 0, 0, 0);
        }
        if (col < NCLS) {
#pragma unroll
            for (int r = 0; r < 4; ++r) {
                int row = s * 16 + q * 4 + r;
                hs2b[(size_t)row * NCLS + col] = f2bf(acc[r] * dis[row]);
            }
        }
    }
}

// ===== agg2: out = dis*(sum + self) + b2 (f32 out) =========================
// row = 20 dwords. 3 edges/round, lane-group g=lane/20 takes edge 3j+g.
// Full 24-edge batches carry NO validity logic; single masked tail batch.

__global__ __launch_bounds__(256) void agg2_kernel(
    const int* __restrict__ ptr, const int* __restrict__ col,
    const unsigned* __restrict__ hs2p, const float* __restrict__ dis,
    const float* __restrict__ b2, float* __restrict__ out, int n)
{
    int wave = threadIdx.x >> 6, lane = threadIdx.x & 63;
    int i = blockIdx.x * 4 + wave;
    if (i >= n) return;
    const int g  = lane / 20;          // edge-group 0..2 (3 = inactive)
    const int gl = lane - g * 20;      // dword within row
    const bool act = g < 3;
    int start = ptr[i], end = ptr[i + 1];
    float acc0 = 0.f, acc1 = 0.f;
    for (int base = start; base < end; base += 64) {
        int m = end - base; if (m > 64) m = 64;
        int myc = (lane < m) ? col[base + lane] : 0;
        int j = 0;
        // full batches: 24 edges each, all valid, no masks
        for (; 24 * (j / 8 + 1) <= m; j += 8) {
            unsigned w[8];
#pragma unroll
            for (int u = 0; u < 8; ++u) {
                int s = __shfl(myc, 3 * (j + u) + g);   // < m <= 64
                w[u] = hs2p[(unsigned)s * 20u + (unsigned)gl];
            }
#pragma unroll
            for (int u = 0; u < 8; ++u) {
                acc0 += __uint_as_float(w[u] << 16);
                acc1 += __uint_as_float(w[u] & 0xffff0000u);
            }
        }
        // masked tail batch
        if (3 * j + g < m || (act && 3 * j < m)) {
            int rounds = (m + 2) / 3;
            for (; j < rounds; j += 8) {
                unsigned w[8]; int ok[8];
#pragma unroll
                for (int u = 0; u < 8; ++u) {
                    int e = 3 * (j + u) + g;
                    ok[u] = act && (e < m);
                    int s = __shfl(myc, ok[u] ? e : 0);
                    w[u] = hs2p[(unsigned)s * 20u + (unsigned)gl];
                }
#pragma unroll
                for (int u = 0; u < 8; ++u) {
                    acc0 += ok[u] ? __uint_as_float(w[u] << 16) : 0.f;
                    acc1 += ok[u] ? __uint_as_float(w[u] & 0xffff0000u) : 0.f;
                }
            }
        }
    }
    // fold the 3 lane-groups (result valid in lanes 0-19)
    float t0 = acc0 + __shfl(acc0, (lane + 20) & 63) + __shfl(acc0, (lane + 40) & 63);
    float t1 = acc1 + __shfl(acc1, (lane + 20) & 63) + __shfl(acc1, (lane + 40) & 63);
    unsigned sw = hs2p[(unsigned)i * 20u + (unsigned)gl];
    float d = dis[i];
    float v0 = (t0 + __uint_as_float(sw << 16)) * d + b2[2 * gl];
    float v1 = (t1 + __uint_as_float(sw & 0xffff0000u)) * d + b2[2 * gl + 1];
    float a = __shfl(v0, lane >> 1);
    float b = __shfl(v1, lane >> 1);
    if (lane < NCLS) out[(size_t)i * NCLS + lane] = (lane & 1) ? b : a;
}

// ================= launch =================

extern "C" void kernel_launch(void* const* d_in, const int* in_sizes, int n_in,
                              void* d_out, int out_size, void* d_ws, size_t ws_size,
                              hipStream_t stream) {
    const float* x  = (const float*)d_in[0];
    const int*   ei = (const int*)d_in[1];
    const float* W1 = (const float*)d_in[2];
    const float* b1 = (const float*)d_in[3];
    const float* W2 = (const float*)d_in[4];
    const float* b2 = (const float*)d_in[5];
    float* out = (float*)d_out;

    const int n = in_sizes[0] / IN_C;        // 100000
    const int E = in_sizes[1] / 2;           // 1600000
    const int B = (n + 127) >> 7;            // 782 buckets of 128 nodes
    const int* src = ei;
    const int* dst = ei + E;

    char* ws = (char*)d_ws;
    size_t off = 0;
    auto alloc = [&](size_t bytes) { char* p = ws + off; off += (bytes + 255) & ~(size_t)255; return p; };
    float* dis  = (float*)alloc((size_t)n * 4);
    int*   ptr  = (int*)  alloc((size_t)(n + 1) * 4);
    int*   col  = (int*)  alloc((size_t)E * 4);
    int*   bcnt = (int*)  alloc((size_t)NB * 4);
    int*   bptr = (int*)  alloc((size_t)(NB + 1) * 4);
    int*   bfill= (int*)  alloc((size_t)NB * 4);
    unsigned short* hs1b = (unsigned short*)alloc((size_t)(n + 1) * HID * 2);    // +1 zero row
    unsigned short* h1b  = (unsigned short*)alloc((size_t)n * HID * 2);
    unsigned short* hs2b = (unsigned short*)alloc((size_t)(n + 1) * NCLS * 2);   // +1 row pad
    int* part = (int*)alloc((size_t)E * 4);

    hipMemsetAsync(bcnt, 0, (size_t)B * 4, stream);
    hipMemsetAsync(hs1b + (size_t)n * HID, 0, HID * 2, stream);   // zero sentinel row
    bhist_kernel<<<(E + CHH - 1) / CHH, 256, 0, stream>>>(dst, bcnt, E, B);
    bscan_kernel<<<1, 256, 0, stream>>>(bcnt, bptr, bfill, B, E);
    scatter_part<<<(E + CHP - 1) / CHP, 256, 0, stream>>>(src, dst, bfill, part, E, B);
    fine_sort<<<B, 256, 0, stream>>>(bptr, part, col, ptr, dis, n, E);

    gemm1_mfma<<<2048, 256, 0, stream>>>(x, W1, dis, hs1b, n);
    agg1_kernel<<<(n + 3) / 4, 256, 0, stream>>>(ptr, col, (const unsigned*)hs1b, dis, b1,
                                                 (unsigned*)h1b, n);
    gemm2_mfma<<<2048, 192, 0, stream>>>(h1b, W2, dis, hs2b, n);
    agg2_kernel<<<(n + 3) / 4, 256, 0, stream>>>(ptr, col, (const unsigned*)hs2b, dis, b2,
                                                 out, n);
}

// Round 11
// 258.259 us; speedup vs baseline: 1.1206x; 1.1206x over previous
//
#include <hip/hip_runtime.h>

#define IN_C 128
#define HID  64
#define NCLS 40
#define CHP  2048     // edges per scatter_part chunk (measured sweet spot)
#define SPT  512      // scatter_part threads
#define CHH  4096     // edges per bhist chunk
#define NB   1024     // padded bucket-array size (B <= 1024)

typedef float f32x4 __attribute__((ext_vector_type(4)));
typedef short s16x8 __attribute__((ext_vector_type(8)));

// ---- bf16 helpers: RTN pack ----
static __device__ inline unsigned short f2bf(float f) {
    unsigned u = __float_as_uint(f);
    return (unsigned short)((u + 0x7FFF + ((u >> 16) & 1)) >> 16);
}

// truncation split: v = hi + lo with hi = top-16-bit truncation
static __device__ inline void split1(float v, unsigned short& hb, unsigned short& lb) {
    hb = (unsigned short)(__float_as_uint(v) >> 16);
    float vhi = __uint_as_float((unsigned)hb << 16);
    lb = (unsigned short)(__float_as_uint(v - vhi) >> 16);
}

static __device__ inline void split8(const f32x4 a0, const f32x4 a1, s16x8& hi, s16x8& lo) {
    float v[8] = {a0.x, a0.y, a0.z, a0.w, a1.x, a1.y, a1.z, a1.w};
#pragma unroll
    for (int j = 0; j < 8; ++j) {
        unsigned short hb, lb;
        split1(v[j], hb, lb);
        hi[j] = (short)hb;
        lo[j] = (short)lb;
    }
}

// ================= bucket histogram: bcnt[b] = #edges with dst>>7 == b ======

__global__ __launch_bounds__(256) void bhist_kernel(
    const int* __restrict__ dst, int* __restrict__ bcnt, int E, int B)
{
    __shared__ int h[NB];
    const int t = threadIdx.x;
    for (int i = t; i < NB; i += 256) h[i] = 0;
    __syncthreads();
    const int base = blockIdx.x * CHH;
    const int nE = min(CHH, E - base);
    for (int k = t; k < nE; k += 256) atomicAdd(&h[dst[base + k] >> 7], 1);
    __syncthreads();
    for (int b = t; b < B; b += 256) { int c = h[b]; if (c) atomicAdd(&bcnt[b], c); }
}

// ================= bucket scan: bptr = exclusive scan(bcnt), bfill = copy ====

__global__ __launch_bounds__(256) void bscan_kernel(
    const int* __restrict__ bcnt, int* __restrict__ bptr, int* __restrict__ bfill,
    int B, int E)
{
    __shared__ int s[256];
    const int t = threadIdx.x;
    int v[4]; int ts = 0;
#pragma unroll
    for (int j = 0; j < 4; ++j) {
        int idx = 4 * t + j;
        v[j] = (idx < B) ? bcnt[idx] : 0;
        ts += v[j];
    }
    s[t] = ts; __syncthreads();
    for (int off = 1; off < 256; off <<= 1) {
        int add = (t >= off) ? s[t - off] : 0;
        __syncthreads();
        s[t] += add;
        __syncthreads();
    }
    int run = s[t] - ts;
#pragma unroll
    for (int j = 0; j < 4; ++j) {
        int idx = 4 * t + j;
        if (idx < B) { bptr[idx] = run; bfill[idx] = run; run += v[j]; }
    }
    if (t == 0) bptr[B] = E;
}

// ====== coarse partition: part[] = edges grouped by dst>>7 =================
// packed word = (src << 7) | (dst & 127).  512 threads: serial phases halved.

__global__ __launch_bounds__(SPT) void scatter_part(
    const int* __restrict__ src, const int* __restrict__ dst,
    int* __restrict__ bfill, int* __restrict__ part, int E, int B)
{
    __shared__ int cnt[NB], soff[NB], gpos[NB], sdata[SPT];
    __shared__ int stage[CHP], destg[CHP];
    const int t = threadIdx.x;
    const int base = blockIdx.x * CHP;
    const int nE = min(CHP, E - base);

    for (int i = t; i < NB; i += SPT) cnt[i] = 0;
    __syncthreads();
    // pass a: histogram by bucket
    for (int k = t; k < nE; k += SPT)
        atomicAdd(&cnt[dst[base + k] >> 7], 1);
    __syncthreads();
    // block-exclusive scan of cnt[0..NB) (thread t owns 2t, 2t+1)
    int v0 = cnt[2 * t], v1 = cnt[2 * t + 1];
    int ts = v0 + v1;
    sdata[t] = ts; __syncthreads();
    for (int off = 1; off < SPT; off <<= 1) {
        int add = (t >= off) ? sdata[t - off] : 0;
        __syncthreads();
        sdata[t] += add;
        __syncthreads();
    }
    int run = sdata[t] - ts;
    soff[2 * t] = run;
    soff[2 * t + 1] = run + v0;
    __syncthreads();
    // claim global runs (one atomic per non-empty (block,bucket))
    for (int b = t; b < B; b += SPT) {
        int c = cnt[b];
        gpos[b] = c ? atomicAdd(&bfill[b], c) : 0;
    }
    __syncthreads();
    for (int i = t; i < NB; i += SPT) cnt[i] = 0;   // reuse as cursor
    __syncthreads();
    // pass b: bin into LDS stage, record global destination
    for (int k = t; k < nE; k += SPT) {
        int d = dst[base + k];
        int b = d >> 7;
        int p = atomicAdd(&cnt[b], 1);
        int o = soff[b] + p;
        stage[o] = (src[base + k] << 7) | (d & 127);
        destg[o] = gpos[b] + p;
    }
    __syncthreads();
    // full-width copy: consecutive k within a run -> consecutive destinations
    for (int k = t; k < nE; k += SPT)
        part[destg[k]] = stage[k];
}

// ====== fine sort within bucket -> CSR col, per-node ptr & dis ==============

__global__ __launch_bounds__(256) void fine_sort(
    const int* __restrict__ bptr, const int* __restrict__ part,
    int* __restrict__ col, int* __restrict__ ptr, float* __restrict__ dis,
    int n, int E)
{
    __shared__ int cnt[128], sc[128], cur[128];
    __shared__ int stage[3072];
    const int t = threadIdx.x;
    const int base = blockIdx.x << 7;
    const int nn = min(128, n - base);
    const int rstart = bptr[blockIdx.x];
    const int rend   = bptr[blockIdx.x + 1];

    if (t < 128) cnt[t] = 0;
    __syncthreads();
    for (int e = rstart + t; e < rend; e += 256)
        atomicAdd(&cnt[part[e] & 127], 1);
    __syncthreads();
    int v = (t < 128) ? cnt[t] : 0;
    if (t < 128) sc[t] = v;
    __syncthreads();
    for (int off = 1; off < 128; off <<= 1) {
        int add = (t < 128 && t >= off) ? sc[t - off] : 0;
        __syncthreads();
        if (t < 128) sc[t] += add;
        __syncthreads();
    }
    if (t < 128) cur[t] = sc[t] - v;
    if (t < nn) {
        ptr[base + t] = rstart + sc[t] - v;
        dis[base + t] = rsqrtf((float)(v + 1));
    }
    if (blockIdx.x == 0 && t == 0) ptr[n] = E;
    __syncthreads();
    for (int e = rstart + t; e < rend; e += 256) {
        int pk = part[e];
        int p = atomicAdd(&cur[pk & 127], 1);
        int s = pk >> 7;
        if (p < 3072) stage[p] = s;
        else col[rstart + p] = s;
    }
    __syncthreads();
    int sz = rend - rstart; if (sz > 3072) sz = 3072;
    for (int j = t; j < sz; j += 256) col[rstart + j] = stage[j];
}

// ====== GEMM1 (MFMA): hs1b = bf16((x @ W1) * dis[i]) ======================

__global__ __launch_bounds__(256) void gemm1_mfma(
    const float* __restrict__ x, const float* __restrict__ W1,
    const float* __restrict__ dis, unsigned short* __restrict__ hs1b, int n)
{
    const int wave = threadIdx.x >> 6;
    const int lane = threadIdx.x & 63;
    const int m    = lane & 15;
    const int q    = lane >> 4;
    const int col  = wave * 16 + m;

    s16x8 bhi[4], blo[4];
#pragma unroll
    for (int t = 0; t < 4; ++t) {
#pragma unroll
        for (int j = 0; j < 8; ++j) {
            int k = t * 32 + q * 8 + j;
            unsigned short hb, lb;
            split1(W1[k * HID + col], hb, lb);
            bhi[t][j] = (short)hb;
            blo[t][j] = (short)lb;
        }
    }

    const int nslab = n >> 4;
    for (int s = blockIdx.x; s < nslab; s += gridDim.x) {
        const float* xrow = x + (size_t)(s * 16 + m) * IN_C;
        f32x4 acc = {0.f, 0.f, 0.f, 0.f};
#pragma unroll
        for (int t = 0; t < 4; ++t) {
            f32x4 a0 = *(const f32x4*)(xrow + t * 32 + q * 8);
            f32x4 a1 = *(const f32x4*)(xrow + t * 32 + q * 8 + 4);
            s16x8 ahi, alo;
            split8(a0, a1, ahi, alo);
            acc = __builtin_amdgcn_mfma_f32_16x16x32_bf16(ahi, bhi[t], acc, 0, 0, 0);
            acc = __builtin_amdgcn_mfma_f32_16x16x32_bf16(alo, bhi[t], acc, 0, 0, 0);
            acc = __builtin_amdgcn_mfma_f32_16x16x32_bf16(ahi, blo[t], acc, 0, 0, 0);
        }
#pragma unroll
        for (int r = 0; r < 4; ++r) {
            int row = s * 16 + q * 4 + r;
            hs1b[(size_t)row * HID + col] = f2bf(acc[r] * dis[row]);
        }
    }
}

// ===== agg1: h1 = relu(dis*(sum + self) + b1), paired u32 gathers ==========
// row = 32 dwords. half 0 (lanes 0-31) even edges, half 1 odd edges.
// ZERO-ROW SENTINEL: lanes >= m carry myc = n (zeroed row); ep <= 63 always,
// so shfl pulls the sentinel for out-of-range edges -> unconditional adds.

__global__ __launch_bounds__(256) void agg1_kernel(
    const int* __restrict__ ptr, const int* __restrict__ col,
    const unsigned* __restrict__ hs1p, const float* __restrict__ dis,
    const float* __restrict__ b1, unsigned* __restrict__ h1p, int n)
{
    int wave = threadIdx.x >> 6, lane = threadIdx.x & 63;
    int i = blockIdx.x * 4 + wave;
    if (i >= n) return;
    const int h  = lane >> 5;
    const int hl = lane & 31;
    const int ZR = n;                       // zeroed sentinel row
    int start = ptr[i], end = ptr[i + 1];
    float acc0 = 0.f, acc1 = 0.f;
    for (int base = start; base < end; base += 64) {
        int m = end - base; if (m > 64) m = 64;
        int myc = (lane < m) ? col[base + lane] : ZR;
        int rounds = (m + 1) >> 1;          // 2 edges per round
        for (int j = 0; j < rounds; j += 8) {
            unsigned w[8];
#pragma unroll
            for (int u = 0; u < 8; ++u) {
                int s = __shfl(myc, 2 * (j + u) + h);   // <= 63 always
                w[u] = hs1p[(unsigned)s * 32u + (unsigned)hl];
            }
#pragma unroll
            for (int u = 0; u < 8; ++u) {
                acc0 += __uint_as_float(w[u] << 16);
                acc1 += __uint_as_float(w[u] & 0xffff0000u);
            }
        }
    }
    float o0 = acc0 + __shfl(acc0, (lane + 32) & 63);
    float o1 = acc1 + __shfl(acc1, (lane + 32) & 63);
    if (lane < 32) {
        unsigned sw = hs1p[(unsigned)i * 32u + (unsigned)lane];   // self-loop
        float d = dis[i];
        float v0 = (o0 + __uint_as_float(sw << 16)) * d + b1[2 * lane];
        float v1 = (o1 + __uint_as_float(sw & 0xffff0000u)) * d + b1[2 * lane + 1];
        v0 = v0 > 0.f ? v0 : 0.f;
        v1 = v1 > 0.f ? v1 : 0.f;
        h1p[(unsigned)i * 32u + (unsigned)lane] = (unsigned)f2bf(v0) | ((unsigned)f2bf(v1) << 16);
    }
}

// ====== GEMM2 (MFMA): hs2b = bf16((h1 @ W2) * dis[i]), h1 native bf16 ======

__global__ __launch_bounds__(192) void gemm2_mfma(
    const unsigned short* __restrict__ h1b, const float* __restrict__ W2,
    const float* __restrict__ dis, unsigned short* __restrict__ hs2b, int n)
{
    const int wave = threadIdx.x >> 6;
    const int lane = threadIdx.x & 63;
    const int m    = lane & 15;
    const int q    = lane >> 4;
    const int col  = wave * 16 + m;

    s16x8 bhi[2], blo[2];
#pragma unroll
    for (int t = 0; t < 2; ++t) {
#pragma unroll
        for (int j = 0; j < 8; ++j) {
            int k = t * 32 + q * 8 + j;
            float w = (col < NCLS) ? W2[k * NCLS + col] : 0.f;
            unsigned short hb, lb;
            split1(w, hb, lb);
            bhi[t][j] = (short)hb;
            blo[t][j] = (short)lb;
        }
    }

    const int nslab = n >> 4;
    for (int s = blockIdx.x; s < nslab; s += gridDim.x) {
        const unsigned short* hrow = h1b + (size_t)(s * 16 + m) * HID;
        f32x4 acc = {0.f, 0.f, 0.f, 0.f};
#pragma unroll
        for (int t = 0; t < 2; ++t) {
            s16x8 ahi = *(const s16x8*)(hrow + t * 32 + q * 8);   // native bf16 A
            acc = __builtin_amdgcn_mfma_f32_16x16x32_bf16(ahi, bhi[t], acc, 0, 0, 0);
            acc = __builtin_amdgcn_mfma_f32_16x16x32_bf16(ahi, blo[t], acc, 0, 0, 0);
        }
        if (col < NCLS) {
#pragma unroll
            for (int r = 0; r < 4; ++r) {
                int row = s * 16 + q * 4 + r;
                hs2b[(size_t)row * NCLS + col] = f2bf(acc[r] * dis[row]);
            }
        }
    }
}

// ===== agg2: out = dis*(sum + self) + b2 (f32 out) =========================
// row = 20 dwords. 3 edges/round, lane-group g=lane/20 takes edge 3j+g.
// Full 24-edge batches carry NO validity logic; ONE wave-uniform tail batch
// (all 64 lanes enter -> shfl sees full wave; inactive groups contribute 0).

__global__ __launch_bounds__(256) void agg2_kernel(
    const int* __restrict__ ptr, const int* __restrict__ col,
    const unsigned* __restrict__ hs2p, const float* __restrict__ dis,
    const float* __restrict__ b2, float* __restrict__ out, int n)
{
    int wave = threadIdx.x >> 6, lane = threadIdx.x & 63;
    int i = blockIdx.x * 4 + wave;
    if (i >= n) return;
    const int g  = lane / 20;          // edge-group 0..2 (3 = inactive)
    const int gl = lane - g * 20;      // dword within row
    const bool act = g < 3;
    int start = ptr[i], end = ptr[i + 1];
    float acc0 = 0.f, acc1 = 0.f;
    for (int base = start; base < end; base += 64) {
        int m = end - base; if (m > 64) m = 64;
        int myc = (lane < m) ? col[base + lane] : 0;
        int j = 0;
        // full batches: 24 edges each, all valid, no masks
        for (; 24 * (j / 8 + 1) <= m; j += 8) {
            unsigned w[8];
#pragma unroll
            for (int u = 0; u < 8; ++u) {
                int s = __shfl(myc, 3 * (j + u) + g);   // < m <= 64
                w[u] = hs2p[(unsigned)s * 20u + (unsigned)gl];
            }
#pragma unroll
            for (int u = 0; u < 8; ++u) {
                acc0 += __uint_as_float(w[u] << 16);
                acc1 += __uint_as_float(w[u] & 0xffff0000u);
            }
        }
        // masked tail batches (wave-uniform condition: all lanes participate)
        int rounds = (m + 2) / 3;
        for (; j < rounds; j += 8) {
            unsigned w[8]; int ok[8];
#pragma unroll
            for (int u = 0; u < 8; ++u) {
                int e = 3 * (j + u) + g;
                ok[u] = act && (e < m);
                int s = __shfl(myc, ok[u] ? e : 0);
                w[u] = hs2p[(unsigned)s * 20u + (unsigned)gl];
            }
#pragma unroll
            for (int u = 0; u < 8; ++u) {
                acc0 += ok[u] ? __uint_as_float(w[u] << 16) : 0.f;
                acc1 += ok[u] ? __uint_as_float(w[u] & 0xffff0000u) : 0.f;
            }
        }
    }
    float t0 = acc0 + __shfl(acc0, (lane + 20) & 63) + __shfl(acc0, (lane + 40) & 63);
    float t1 = acc1 + __shfl(acc1, (lane + 20) & 63) + __shfl(acc1, (lane + 40) & 63);
    unsigned sw = hs2p[(unsigned)i * 20u + (unsigned)gl];
    float d = dis[i];
    float v0 = (t0 + __uint_as_float(sw << 16)) * d + b2[2 * gl];
    float v1 = (t1 + __uint_as_float(sw & 0xffff0000u)) * d + b2[2 * gl + 1];
    float a = __shfl(v0, lane >> 1);
    float b = __shfl(v1, lane >> 1);
    if (lane < NCLS) out[(size_t)i * NCLS + lane] = (lane & 1) ? b : a;
}

// ================= launch =================

extern "C" void kernel_launch(void* const* d_in, const int* in_sizes, int n_in,
                              void* d_out, int out_size, void* d_ws, size_t ws_size,
                              hipStream_t stream) {
    const float* x  = (const float*)d_in[0];
    const int*   ei = (const int*)d_in[1];
    const float* W1 = (const float*)d_in[2];
    const float* b1 = (const float*)d_in[3];
    const float* W2 = (const float*)d_in[4];
    const float* b2 = (const float*)d_in[5];
    float* out = (float*)d_out;

    const int n = in_sizes[0] / IN_C;        // 100000
    const int E = in_sizes[1] / 2;           // 1600000
    const int B = (n + 127) >> 7;            // 782 buckets of 128 nodes
    const int* src = ei;
    const int* dst = ei + E;

    char* ws = (char*)d_ws;
    size_t off = 0;
    auto alloc = [&](size_t bytes) { char* p = ws + off; off += (bytes + 255) & ~(size_t)255; return p; };
    float* dis  = (float*)alloc((size_t)n * 4);
    int*   ptr  = (int*)  alloc((size_t)(n + 1) * 4);
    int*   col  = (int*)  alloc((size_t)E * 4);
    int*   bcnt = (int*)  alloc((size_t)NB * 4);
    int*   bptr = (int*)  alloc((size_t)(NB + 1) * 4);
    int*   bfill= (int*)  alloc((size_t)NB * 4);
    unsigned short* hs1b = (unsigned short*)alloc((size_t)(n + 1) * HID * 2);    // +1 zero row
    unsigned short* h1b  = (unsigned short*)alloc((size_t)n * HID * 2);
    unsigned short* hs2b = (unsigned short*)alloc((size_t)(n + 1) * NCLS * 2);   // +1 row pad
    int* part = (int*)alloc((size_t)E * 4);

    hipMemsetAsync(bcnt, 0, (size_t)B * 4, stream);
    hipMemsetAsync(hs1b + (size_t)n * HID, 0, HID * 2, stream);   // zero sentinel row
    bhist_kernel<<<(E + CHH - 1) / CHH, 256, 0, stream>>>(dst, bcnt, E, B);
    bscan_kernel<<<1, 256, 0, stream>>>(bcnt, bptr, bfill, B, E);
    scatter_part<<<(E + CHP - 1) / CHP, SPT, 0, stream>>>(src, dst, bfill, part, E, B);
    fine_sort<<<B, 256, 0, stream>>>(bptr, part, col, ptr, dis, n, E);

    gemm1_mfma<<<2048, 256, 0, stream>>>(x, W1, dis, hs1b, n);
    agg1_kernel<<<(n + 3) / 4, 256, 0, stream>>>(ptr, col, (const unsigned*)hs1b, dis, b1,
                                                 (unsigned*)h1b, n);
    gemm2_mfma<<<2048, 192, 0, stream>>>(h1b, W2, dis, hs2b, n);
    agg2_kernel<<<(n + 3) / 4, 256, 0, stream>>>(ptr, col, (const unsigned*)hs2b, dis, b2,
                                                 out, n);
}